// Round 1
// baseline (485.584 us; speedup 1.0000x reference)
//
#include <hip/hip_runtime.h>

#define L_   8192
#define H_   128
#define T_   4095      // (8192-3)/2 + 1
#define CH_  16        // scan chunk length
#define NC_  256       // number of chunks (255 full + 1 of 15)

typedef __bf16 bf16x8 __attribute__((ext_vector_type(8)));
typedef unsigned short ushort8 __attribute__((ext_vector_type(8)));
typedef unsigned short us4 __attribute__((ext_vector_type(4)));
typedef float f32x4 __attribute__((ext_vector_type(4)));

__device__ __forceinline__ unsigned short f2bf(float f) {
    // round-to-nearest-even fp32 -> bf16 bits
    unsigned int u = __builtin_bit_cast(unsigned int, f);
    u += 0x7fffu + ((u >> 16) & 1u);
    return (unsigned short)(u >> 16);
}

// lam^e for block-uniform e in [1,16]: 3 squares + <=4 selected muls.
__device__ __forceinline__ float powe(float l, int e) {
    float r = (e & 1) ? l : 1.f;
    float b = l * l;            // l^2
    if (e & 2) r *= b;
    b *= b;                     // l^4
    if (e & 4) r *= b;
    b *= b;                     // l^8
    if (e & 8) r *= b;
    if (e & 16) r = b * b;      // e==16 exactly
    return r;
}

// ---------------- pass A: local scan, materialize fp32 zs_local into `out` ----------
// block = (chunk c, a-tile of 16), 256 threads: thread owns (a_l = tid>>4, 8 d's).
// Double-buffered y/xa staging -> ONE barrier per t-step; X prefetched 1 step ahead.
// Writes zs_local[t][a][d] (carry-free prefix) into out; also os[t] (blockIdx.y==0).
__global__ __launch_bounds__(256) void passA_kernel(const float* __restrict__ X,
                                                    const float* __restrict__ Lam,
                                                    const float* __restrict__ wq,
                                                    const float* __restrict__ Dv,
                                                    float* __restrict__ out,
                                                    float* __restrict__ os) {
    // y_s rows are XOR-swizzled (byte ^= 16 when d&32) so the 16-lane stride-32B
    // vector reads hit 8 distinct bank-quads (conflict-free b128).
    __shared__ float y_s[2][3][128];
    __shared__ float xa_s[2][3][16];

    const int tid = threadIdx.x;
    const int c   = blockIdx.x;
    const int a0  = blockIdx.y * 16;
    const int a_l = tid >> 4;
    const int dg  = tid & 15;
    const int d0  = dg * 8;

    float z[8], lam[8];
    {
        const float* lp = Lam + (size_t)(a0 + a_l) * H_ + d0;
        #pragma unroll
        for (int j = 0; j < 8; ++j) { lam[j] = lp[j]; z[j] = 0.f; }
    }
    const float w00 = wq[0], w01 = wq[1], w02 = wq[2];
    const float w10 = wq[3], w11 = wq[4], w12 = wq[5];
    const float w20 = wq[6], w21 = wq[7], w22 = wq[8];
    const float dv0 = Dv[0], dv1 = Dv[1], dv2 = Dv[2];

    const bool ystage = tid < 128;
    const bool astage = (tid >= 128) && (tid < 176);
    const bool do_os  = (blockIdx.y == 0) && ystage;
    const int  wA = (tid - 128) >> 4, aA = (tid - 128) & 15;

    const int t0 = c * CH_, t1 = min(t0 + CH_, T_);

    float xd0 = 0.f, xd1 = 0.f, xd2 = 0.f, xav = 0.f;
    {
        const float* xr = X + (size_t)(2 * t0) * H_;
        if (ystage)      { xd0 = xr[tid]; xd1 = xr[H_ + tid]; xd2 = xr[2 * H_ + tid]; }
        else if (astage) { xav = xr[wA * H_ + a0 + aA]; }
    }
    // stage buffer 0 for t0
    if (ystage) {
        const int sw = (4 * tid) ^ ((tid & 32) >> 1);
        char* yb0 = (char*)&y_s[0][0][0];
        *(float*)(yb0 + sw)        = w00 * xd0 + w01 * xd1 + w02 * xd2;
        *(float*)(yb0 + 512 + sw)  = w10 * xd0 + w11 * xd1 + w12 * xd2;
        *(float*)(yb0 + 1024 + sw) = w20 * xd0 + w21 * xd1 + w22 * xd2;
        if (do_os) os[(size_t)t0 * H_ + tid] = dv0 * xd0 + dv1 * xd1 + dv2 * xd2;
    } else if (astage) {
        xa_s[0][wA][aA] = xav;
    }
    __syncthreads();

    int p = 0;
    for (int t = t0; t < t1; ++t) {
        const bool more = (t + 1 < t1);
        if (more) {   // prefetch X for t+1 (latency hidden under scan+store)
            const float* xr = X + (size_t)(2 * (t + 1)) * H_;
            if (ystage)      { xd0 = xr[tid]; xd1 = xr[H_ + tid]; xd2 = xr[2 * H_ + tid]; }
            else if (astage) { xav = xr[wA * H_ + a0 + aA]; }
        }
        // consume buffer p
        const float xa0 = xa_s[p][0][a_l], xa1 = xa_s[p][1][a_l], xa2 = xa_s[p][2][a_l];
        const char* yb = (const char*)y_s + p * 1536;
        const int s4 = (dg & 4) << 2;
        const int lo = (32 * dg) ^ s4;         // j=0..3
        const int hi = (32 * dg + 16) ^ s4;    // j=4..7
        f32x4 yl0 = *(const f32x4*)(yb + lo),        yh0 = *(const f32x4*)(yb + hi);
        f32x4 yl1 = *(const f32x4*)(yb + 512 + lo),  yh1 = *(const f32x4*)(yb + 512 + hi);
        f32x4 yl2 = *(const f32x4*)(yb + 1024 + lo), yh2 = *(const f32x4*)(yb + 1024 + hi);
        #pragma unroll
        for (int j = 0; j < 4; ++j) {
            float u  = xa0 * yl0[j] + xa1 * yl1[j] + xa2 * yl2[j];
            z[j]     = fmaf(lam[j], z[j], u);
            float u2 = xa0 * yh0[j] + xa1 * yh1[j] + xa2 * yh2[j];
            z[j + 4] = fmaf(lam[j + 4], z[j + 4], u2);
        }
        float* op = out + (size_t)t * (H_ * H_) + (size_t)(a0 + a_l) * H_ + d0;
        f32x4 zlo = {z[0], z[1], z[2], z[3]};
        f32x4 zhi = {z[4], z[5], z[6], z[7]};
        *(f32x4*)op       = zlo;
        *(f32x4*)(op + 4) = zhi;
        // stage t+1 into buffer p^1 (consumed-last-iter; barrier below fences it)
        if (more) {
            if (ystage) {
                const int sw = (4 * tid) ^ ((tid & 32) >> 1);
                char* ybn = (char*)y_s + (p ^ 1) * 1536;
                *(float*)(ybn + sw)        = w00 * xd0 + w01 * xd1 + w02 * xd2;
                *(float*)(ybn + 512 + sw)  = w10 * xd0 + w11 * xd1 + w12 * xd2;
                *(float*)(ybn + 1024 + sw) = w20 * xd0 + w21 * xd1 + w22 * xd2;
                if (do_os) os[(size_t)(t + 1) * H_ + tid] = dv0 * xd0 + dv1 * xd1 + dv2 * xd2;
            } else if (astage) {
                xa_s[p ^ 1][wA][aA] = xav;
            }
        }
        __syncthreads();
        p ^= 1;
    }
}

// ---------------- pass 2: cross-chunk scan over chunk-end slices of zs_local -------
// carry[c] = sum_{c'<c} lam^(16*(c-1-c')) * end(c'), end(c) read from out buffer.
__global__ __launch_bounds__(256) void pass2_kernel(const float* __restrict__ Lam,
                                                    const float* __restrict__ zsl,
                                                    float* __restrict__ carry) {
    const int e = blockIdx.x * 256 + threadIdx.x;
    const float lam = Lam[e];
    float l2 = lam * lam, l4 = l2 * l2, l8 = l4 * l4;
    const float l16 = l8 * l8;
    float z = 0.f;
    for (int cb = 0; cb < NC_; cb += 8) {
        float tmp[8];
        #pragma unroll
        for (int i = 0; i < 8; ++i) {
            const int cc = cb + i;
            tmp[i] = (cc < NC_ - 1)
                   ? zsl[(size_t)(cc * CH_ + CH_ - 1) * (H_ * H_) + e] : 0.f;
        }
        #pragma unroll
        for (int i = 0; i < 8; ++i) {
            carry[(size_t)(cb + i) * (H_ * H_) + e] = z;
            z = fmaf(l16, z, tmp[i]);
        }
    }
}

// ---------------- pass C: fully t-parallel fixup + GEMM, in place over `out` -------
// block = one t (4095 blocks, 256 threads, ONE barrier). Reads the 64KB fp32
// zs_local[t] tile (coalesced), zfull = zsl + lam^(s+1)*carry[c], bf16 -> swizzled
// LDS, 128x128x128 MFMA vs C, stores out[t][h][a] over the same 64KB region.
__global__ __launch_bounds__(256) void passC_kernel(const float* __restrict__ Lam,
                                                    const float* __restrict__ Cm,
                                                    const float* __restrict__ carry,
                                                    float* __restrict__ out) {
    __shared__ unsigned short zs[H_ * H_];   // 32 KB bf16, XOR-swizzled rows (256B pitch)

    const int t   = blockIdx.x;
    const int c   = t >> 4;
    const int e   = (t & 15) + 1;            // lam exponent, block-uniform
    const int tid = threadIdx.x;
    const int lane = tid & 63, wave = tid >> 6;
    const int m = lane & 15, q = lane >> 4;

    // ---- phase 1: coalesced read + carry fixup + bf16 -> LDS ----
    const size_t tb = (size_t)t << 14;
    const float* zp = out   + tb + (size_t)tid * 4;
    const float* cp = carry + ((size_t)c << 14) + (size_t)tid * 4;
    const float* lp = Lam   + (size_t)tid * 4;
    const int r0   = tid >> 5;               // row offset within 8-row group
    const int colb = (tid & 31) * 8;         // byte col (4 bf16 = 8B)
    #pragma unroll
    for (int i = 0; i < 16; ++i) {
        const int off = i * 1024;
        f32x4 zv = *(const f32x4*)(zp + off);
        f32x4 cv = *(const f32x4*)(cp + off);
        f32x4 lv = *(const f32x4*)(lp + off);
        us4 zb;
        #pragma unroll
        for (int j = 0; j < 4; ++j)
            zb[j] = f2bf(fmaf(powe(lv[j], e), cv[j], zv[j]));
        const int a = i * 8 + r0;
        *(us4*)((char*)zs + a * 256 + (colb ^ ((a & 15) << 4))) = zb;
    }

    // ---- B-fragments from C (loaded late to keep phase-1 register peak low) ----
    ushort8 cfrag[2][4];
    #pragma unroll
    for (int ni = 0; ni < 2; ++ni) {
        const int h = (wave * 2 + ni) * 16 + m;
        #pragma unroll
        for (int kt = 0; kt < 4; ++kt) {
            const float* src = Cm + h * H_ + kt * 32 + q * 8;
            f32x4 c0 = *(const f32x4*)src;
            f32x4 c1 = *(const f32x4*)(src + 4);
            ushort8 v;
            #pragma unroll
            for (int j = 0; j < 4; ++j) { v[j] = f2bf(c0[j]); v[j + 4] = f2bf(c1[j]); }
            cfrag[ni][kt] = v;
        }
    }
    __syncthreads();

    // ---- phase 2: MFMA. A = zs (M=a), B = C (N=h); D[a,h] -> dwordx4 stores ----
    f32x4 acc[8][2] = {};
    #pragma unroll
    for (int kt = 0; kt < 4; ++kt) {
        const int cb = (64 * kt + 16 * q) ^ (m << 4);
        #pragma unroll
        for (int mi = 0; mi < 8; ++mi) {
            bf16x8 za = *(const bf16x8*)((char*)zs + (mi * 16 + m) * 256 + cb);
            #pragma unroll
            for (int ni = 0; ni < 2; ++ni)
                acc[mi][ni] = __builtin_amdgcn_mfma_f32_16x16x32_bf16(
                    za, __builtin_bit_cast(bf16x8, cfrag[ni][kt]), acc[mi][ni], 0, 0, 0);
        }
    }
    float* ob = out + tb;
    #pragma unroll
    for (int mi = 0; mi < 8; ++mi) {
        #pragma unroll
        for (int ni = 0; ni < 2; ++ni) {
            const int h = (wave * 2 + ni) * 16 + m;
            *(f32x4*)&ob[(size_t)h * H_ + mi * 16 + q * 4] = acc[mi][ni];
        }
    }
}

extern "C" void kernel_launch(void* const* d_in, const int* in_sizes, int n_in,
                              void* d_out, int out_size, void* d_ws, size_t ws_size,
                              hipStream_t stream) {
    const float* X   = (const float*)d_in[0];   // (L, H)
    const float* Lam = (const float*)d_in[1];   // (H, H)
    const float* Cm  = (const float*)d_in[2];   // (H, H)
    const float* wq  = (const float*)d_in[3];   // (3, 3)
    const float* Dv  = (const float*)d_in[4];   // (3,)
    float* out = (float*)d_out;                 // zs_out (T,H,H) then os (T,H)
    float* os  = out + (size_t)T_ * H_ * H_;
    float* cry = (float*)d_ws;                  // NC_ * H*H floats = 16 MiB (same as before)

    passA_kernel<<<dim3(NC_, 8), 256, 0, stream>>>(X, Lam, wq, Dv, out, os);
    pass2_kernel<<<64, 256, 0, stream>>>(Lam, out, cry);
    passC_kernel<<<T_, 256, 0, stream>>>(Lam, Cm, cry, out);
}

// Round 2
// 459.988 us; speedup vs baseline: 1.0556x; 1.0556x over previous
//
#include <hip/hip_runtime.h>

#define L_   8192
#define H_   128
#define T_   4095      // (8192-3)/2 + 1
#define CH_  16        // scan chunk length
#define NC_  256       // number of chunks (255 full + 1 of 15)
#define HH_  (H_ * H_) // 16384
// Cbf (bf16 B-fragments of C, 32 KB) lives in the unused chunk-255 slot of ebuf:
// chunk 255's end value is never consumed by pass2 (carry[c] needs ends[0..254]).
#define CBF_OFF ((size_t)(NC_ - 1) * HH_)   // float offset into ws

typedef __bf16 bf16x8 __attribute__((ext_vector_type(8)));
typedef unsigned short ushort8 __attribute__((ext_vector_type(8)));
typedef float f32x4 __attribute__((ext_vector_type(4)));

__device__ __forceinline__ unsigned short f2bf(float f) {
    // round-to-nearest-even fp32 -> bf16 bits
    unsigned int u = __builtin_bit_cast(unsigned int, f);
    u += 0x7fffu + ((u >> 16) & 1u);
    return (unsigned short)(u >> 16);
}

// ---------------- pass 0: pack C into bf16 B-fragment order ----------------
// frag (nt, kt): lane l holds B[k = kt*32 + (l>>4)*8 + j][n = nt*16 + (l&15)]
//              = Cm[nt*16 + (l&15)][kt*32 + (l>>4)*8 + j]   (8 bf16 = 16 B).
// Stored at Cbf[(frag*64 + lane)*8 ..] so pass3's per-frag load is 1 KB coalesced.
__global__ __launch_bounds__(256) void pass0_kernel(const float* __restrict__ Cm,
                                                    unsigned short* __restrict__ Cbf) {
    const int gid  = blockIdx.x * 256 + threadIdx.x;   // 0..2047 = 32 frags * 64 lanes
    const int frag = gid >> 6, lane = gid & 63;
    const int nt = frag >> 2, kt = frag & 3;
    const int n  = nt * 16 + (lane & 15);
    const int k0 = kt * 32 + (lane >> 4) * 8;
    const float* src = Cm + (size_t)n * H_ + k0;
    ushort8 v;
    #pragma unroll
    for (int j = 0; j < 8; ++j) v[j] = f2bf(src[j]);
    *(ushort8*)(Cbf + (size_t)gid * 8) = v;
}

// ---------------- pass 1: barrier-free per-chunk local scan ends ----------------
// block = (chunk c in 0..254, a-tile of 16), 256 threads. Thread owns
// (a = a0 + (tid&15), d = (tid>>4)*8 .. +8) and recomputes y = wq@x itself from
// X (L2/L3-resident) — no LDS, no __syncthreads, fully pipelineable.
__global__ __launch_bounds__(256) void pass1_kernel(const float* __restrict__ X,
                                                    const float* __restrict__ Lam,
                                                    const float* __restrict__ wq,
                                                    float* __restrict__ ebuf) {
    const int tid = threadIdx.x;
    const int c   = blockIdx.x;            // 0..254 (chunk 255's end is unused)
    const int a0  = blockIdx.y * 16;
    const int a   = a0 + (tid & 15);
    const int d0  = (tid >> 4) * 8;

    float z[8], lam[8];
    {
        const float* lp = Lam + (size_t)a * H_ + d0;
        #pragma unroll
        for (int j = 0; j < 8; ++j) { lam[j] = lp[j]; z[j] = 0.f; }
    }
    const float w00 = wq[0], w01 = wq[1], w02 = wq[2];
    const float w10 = wq[3], w11 = wq[4], w12 = wq[5];
    const float w20 = wq[6], w21 = wq[7], w22 = wq[8];

    const int t0 = c * CH_;
    for (int t = t0; t < t0 + CH_; ++t) {
        const float* xr = X + (size_t)(2 * t) * H_;
        f32x4 x0a = *(const f32x4*)(xr + d0),           x0b = *(const f32x4*)(xr + d0 + 4);
        f32x4 x1a = *(const f32x4*)(xr + H_ + d0),      x1b = *(const f32x4*)(xr + H_ + d0 + 4);
        f32x4 x2a = *(const f32x4*)(xr + 2 * H_ + d0),  x2b = *(const f32x4*)(xr + 2 * H_ + d0 + 4);
        const float xa0 = xr[a], xa1 = xr[H_ + a], xa2 = xr[2 * H_ + a];
        #pragma unroll
        for (int j = 0; j < 4; ++j) {
            {
                const float y0 = w00 * x0a[j] + w01 * x1a[j] + w02 * x2a[j];
                const float y1 = w10 * x0a[j] + w11 * x1a[j] + w12 * x2a[j];
                const float y2 = w20 * x0a[j] + w21 * x1a[j] + w22 * x2a[j];
                z[j] = fmaf(lam[j], z[j], xa0 * y0 + xa1 * y1 + xa2 * y2);
            }
            {
                const float y0 = w00 * x0b[j] + w01 * x1b[j] + w02 * x2b[j];
                const float y1 = w10 * x0b[j] + w11 * x1b[j] + w12 * x2b[j];
                const float y2 = w20 * x0b[j] + w21 * x1b[j] + w22 * x2b[j];
                z[j + 4] = fmaf(lam[j + 4], z[j + 4], xa0 * y0 + xa1 * y1 + xa2 * y2);
            }
        }
    }
    float* ep = ebuf + (size_t)c * HH_ + (size_t)a * H_ + d0;
    f32x4 zlo = {z[0], z[1], z[2], z[3]};
    f32x4 zhi = {z[4], z[5], z[6], z[7]};
    *(f32x4*)ep       = zlo;
    *(f32x4*)(ep + 4) = zhi;
}

// ---------------- pass 2: cross-chunk scan, in place ebuf -> carry ----------------
// After this, slot c (c=0..254) holds carry[c+1]; chunk 0's carry is implicit zero.
__global__ __launch_bounds__(256) void pass2_kernel(const float* __restrict__ Lam,
                                                    float* __restrict__ ebuf) {
    const int e = blockIdx.x * 256 + threadIdx.x;
    const float lam = Lam[e];
    float p2 = lam * lam, p4 = p2 * p2, p8 = p4 * p4;
    const float l16 = p8 * p8;
    float z = 0.f;
    for (int cb = 0; cb < 248; cb += 8) {
        float tmp[8];
        #pragma unroll
        for (int i = 0; i < 8; ++i) tmp[i] = ebuf[(size_t)(cb + i) * HH_ + e];
        #pragma unroll
        for (int i = 0; i < 8; ++i) {
            z = fmaf(l16, z, tmp[i]);
            ebuf[(size_t)(cb + i) * HH_ + e] = z;   // slot c <- carry[c+1]
        }
    }
    {   // tail: chunks 248..254
        float tmp[7];
        #pragma unroll
        for (int i = 0; i < 7; ++i) tmp[i] = ebuf[(size_t)(248 + i) * HH_ + e];
        #pragma unroll
        for (int i = 0; i < 7; ++i) {
            z = fmaf(l16, z, tmp[i]);
            ebuf[(size_t)(248 + i) * HH_ + e] = z;
        }
    }
}

// ---------------- pass 3: barrier-free scan-replay + MFMA, zero LDS ----------------
// block = ONE wave (64 threads): (chunk c, a-tile of 16). Lane owns a = a0+(lane&15)
// and d-chunks k = cc*32 + (lane>>4)*8 — exactly the 16x16x32 A-fragment layout, so
// the scan registers ARE the MFMA A operand. B streams from Cbf (L1-resident, 1 KB
// coalesced per frag). No __syncthreads anywhere; out is write-only.
__global__ __launch_bounds__(64, 2) void pass3_kernel(const float* __restrict__ X,
                                                      const float* __restrict__ Lam,
                                                      const float* __restrict__ wq,
                                                      const float* __restrict__ Dv,
                                                      const float* __restrict__ ws,
                                                      float* __restrict__ out,
                                                      float* __restrict__ os) {
    const int lane = threadIdx.x;
    const int c    = blockIdx.x;
    const int a0   = blockIdx.y * 16;
    const int m    = lane & 15, q = lane >> 4;
    const int a    = a0 + m;
    const unsigned short* Cbf = (const unsigned short*)(ws + CBF_OFF);

    float z[4][8], lam[4][8];
    #pragma unroll
    for (int cc = 0; cc < 4; ++cc) {
        const int k0 = cc * 32 + q * 8;
        const float* lp = Lam + (size_t)a * H_ + k0;
        #pragma unroll
        for (int j = 0; j < 8; ++j) lam[cc][j] = lp[j];
        if (c == 0) {
            #pragma unroll
            for (int j = 0; j < 8; ++j) z[cc][j] = 0.f;
        } else {
            const float* cp = ws + (size_t)(c - 1) * HH_ + (size_t)a * H_ + k0;
            #pragma unroll
            for (int j = 0; j < 8; ++j) z[cc][j] = cp[j];
        }
    }
    const float w00 = wq[0], w01 = wq[1], w02 = wq[2];
    const float w10 = wq[3], w11 = wq[4], w12 = wq[5];
    const float w20 = wq[6], w21 = wq[7], w22 = wq[8];
    const float dv0 = Dv[0], dv1 = Dv[1], dv2 = Dv[2];
    const bool do_os = (blockIdx.y == 0);

    const int t0 = c * CH_, t1 = min(t0 + CH_, T_);
    for (int t = t0; t < t1; ++t) {
        const float* xr = X + (size_t)(2 * t) * H_;
        const float xa0 = xr[a], xa1 = xr[H_ + a], xa2 = xr[2 * H_ + a];
        ushort8 za[4];
        #pragma unroll
        for (int cc = 0; cc < 4; ++cc) {
            const int k0 = cc * 32 + q * 8;
            f32x4 x0a = *(const f32x4*)(xr + k0),          x0b = *(const f32x4*)(xr + k0 + 4);
            f32x4 x1a = *(const f32x4*)(xr + H_ + k0),     x1b = *(const f32x4*)(xr + H_ + k0 + 4);
            f32x4 x2a = *(const f32x4*)(xr + 2 * H_ + k0), x2b = *(const f32x4*)(xr + 2 * H_ + k0 + 4);
            ushort8 zb;
            #pragma unroll
            for (int j = 0; j < 4; ++j) {
                {
                    const float y0 = w00 * x0a[j] + w01 * x1a[j] + w02 * x2a[j];
                    const float y1 = w10 * x0a[j] + w11 * x1a[j] + w12 * x2a[j];
                    const float y2 = w20 * x0a[j] + w21 * x1a[j] + w22 * x2a[j];
                    z[cc][j] = fmaf(lam[cc][j], z[cc][j], xa0 * y0 + xa1 * y1 + xa2 * y2);
                    zb[j] = f2bf(z[cc][j]);
                }
                {
                    const float y0 = w00 * x0b[j] + w01 * x1b[j] + w02 * x2b[j];
                    const float y1 = w10 * x0b[j] + w11 * x1b[j] + w12 * x2b[j];
                    const float y2 = w20 * x0b[j] + w21 * x1b[j] + w22 * x2b[j];
                    z[cc][j + 4] = fmaf(lam[cc][j + 4], z[cc][j + 4], xa0 * y0 + xa1 * y1 + xa2 * y2);
                    zb[j + 4] = f2bf(z[cc][j + 4]);
                }
            }
            za[cc] = zb;
        }
        if (do_os) {
            const float s0 = xr[lane], s1 = xr[H_ + lane], s2 = xr[2 * H_ + lane];
            os[(size_t)t * H_ + lane] = dv0 * s0 + dv1 * s1 + dv2 * s2;
            const float u0 = xr[64 + lane], u1 = xr[H_ + 64 + lane], u2 = xr[2 * H_ + 64 + lane];
            os[(size_t)t * H_ + 64 + lane] = dv0 * u0 + dv1 * u1 + dv2 * u2;
        }
        // MFMA: A = za (M=a), B = Cbf frags (N=h). D: col=m -> h, row=q*4+r -> a.
        float* ob = out + (size_t)t * HH_ + a0 + q * 4;
        #pragma unroll
        for (int nt = 0; nt < 8; ++nt) {
            f32x4 acc = {0.f, 0.f, 0.f, 0.f};
            #pragma unroll
            for (int cc = 0; cc < 4; ++cc) {
                ushort8 cb = *(const ushort8*)(Cbf + ((size_t)(nt * 4 + cc) * 64 + lane) * 8);
                acc = __builtin_amdgcn_mfma_f32_16x16x32_bf16(
                    __builtin_bit_cast(bf16x8, za[cc]),
                    __builtin_bit_cast(bf16x8, cb), acc, 0, 0, 0);
            }
            *(f32x4*)(ob + (size_t)(nt * 16 + m) * H_) = acc;
        }
    }
}

extern "C" void kernel_launch(void* const* d_in, const int* in_sizes, int n_in,
                              void* d_out, int out_size, void* d_ws, size_t ws_size,
                              hipStream_t stream) {
    const float* X   = (const float*)d_in[0];   // (L, H)
    const float* Lam = (const float*)d_in[1];   // (H, H)
    const float* Cm  = (const float*)d_in[2];   // (H, H)
    const float* wq  = (const float*)d_in[3];   // (3, 3)
    const float* Dv  = (const float*)d_in[4];   // (3,)
    float* out  = (float*)d_out;                // zs_out (T,H,H) then os (T,H)
    float* os   = out + (size_t)T_ * HH_;
    float* ebuf = (float*)d_ws;                 // 255 end/carry slots + Cbf = 16 MiB

    pass0_kernel<<<8, 256, 0, stream>>>(Cm, (unsigned short*)(ebuf + CBF_OFF));
    pass1_kernel<<<dim3(NC_ - 1, 8), 256, 0, stream>>>(X, Lam, wq, ebuf);
    pass2_kernel<<<64, 256, 0, stream>>>(Lam, ebuf);
    pass3_kernel<<<dim3(NC_, 8), 64, 0, stream>>>(X, Lam, wq, Dv, ebuf, out, os);
}

// Round 3
// 419.376 us; speedup vs baseline: 1.1579x; 1.0968x over previous
//
#include <hip/hip_runtime.h>

#define L_   8192
#define H_   128
#define T_   4095      // (8192-3)/2 + 1
#define CH_  16        // scan chunk length
#define NC_  256       // number of chunks (255 full + 1 of 15)
#define HH_  (H_ * H_) // 16384

typedef __bf16 bf16x8 __attribute__((ext_vector_type(8)));
typedef unsigned short ushort8 __attribute__((ext_vector_type(8)));
typedef float f32x4 __attribute__((ext_vector_type(4)));
typedef int v4i __attribute__((ext_vector_type(4)));

__device__ __forceinline__ unsigned short f2bf(float f) {
    // round-to-nearest-even fp32 -> bf16 bits (matches all previously passing rounds)
    unsigned int u = __builtin_bit_cast(unsigned int, f);
    u += 0x7fffu + ((u >> 16) & 1u);
    return (unsigned short)(u >> 16);
}

// ---------------- pass 1: barrier-free per-chunk local scan ends (g-trick) --------
// u[a][d] = sum_v g_v * x_v[d],  g_v = sum_w wq[w][v] * x[w][a]  (4 ops/elem).
__global__ __launch_bounds__(256) void pass1_kernel(const float* __restrict__ X,
                                                    const float* __restrict__ Lam,
                                                    const float* __restrict__ wq,
                                                    float* __restrict__ ebuf) {
    const int tid = threadIdx.x;
    const int c   = blockIdx.x;            // 0..254 (chunk 255's end is unused)
    const int a   = blockIdx.y * 16 + (tid & 15);
    const int d0  = (tid >> 4) * 8;

    float z[8], lam[8];
    {
        const float* lp = Lam + (size_t)a * H_ + d0;
        #pragma unroll
        for (int j = 0; j < 8; ++j) { lam[j] = lp[j]; z[j] = 0.f; }
    }
    const float wq0 = wq[0], wq1 = wq[1], wq2 = wq[2];
    const float wq3 = wq[3], wq4 = wq[4], wq5 = wq[5];
    const float wq6 = wq[6], wq7 = wq[7], wq8 = wq[8];

    const int t0 = c * CH_;
    for (int t = t0; t < t0 + CH_; ++t) {
        const float* xr = X + (size_t)(2 * t) * H_;
        const float xa0 = xr[a], xa1 = xr[H_ + a], xa2 = xr[2 * H_ + a];
        const float g0 = wq0 * xa0 + wq3 * xa1 + wq6 * xa2;
        const float g1 = wq1 * xa0 + wq4 * xa1 + wq7 * xa2;
        const float g2 = wq2 * xa0 + wq5 * xa1 + wq8 * xa2;
        f32x4 x0a = *(const f32x4*)(xr + d0),           x0b = *(const f32x4*)(xr + d0 + 4);
        f32x4 x1a = *(const f32x4*)(xr + H_ + d0),      x1b = *(const f32x4*)(xr + H_ + d0 + 4);
        f32x4 x2a = *(const f32x4*)(xr + 2 * H_ + d0),  x2b = *(const f32x4*)(xr + 2 * H_ + d0 + 4);
        #pragma unroll
        for (int j = 0; j < 4; ++j) {
            z[j]     = fmaf(lam[j],     z[j],     g0 * x0a[j] + g1 * x1a[j] + g2 * x2a[j]);
            z[j + 4] = fmaf(lam[j + 4], z[j + 4], g0 * x0b[j] + g1 * x1b[j] + g2 * x2b[j]);
        }
    }
    float* ep = ebuf + (size_t)c * HH_ + (size_t)a * H_ + d0;
    f32x4 zlo = {z[0], z[1], z[2], z[3]};
    f32x4 zhi = {z[4], z[5], z[6], z[7]};
    *(f32x4*)ep       = zlo;
    *(f32x4*)(ep + 4) = zhi;
}

// ---------------- pass 2: cross-chunk scan, in place ebuf -> carry ----------------
// After this, slot c (c=0..254) holds carry for chunk c+1; chunk 0 carry = 0.
__global__ __launch_bounds__(256) void pass2_kernel(const float* __restrict__ Lam,
                                                    float* __restrict__ ebuf) {
    const int e = blockIdx.x * 256 + threadIdx.x;
    const float lam = Lam[e];
    float p2 = lam * lam, p4 = p2 * p2, p8 = p4 * p4;
    const float l16 = p8 * p8;
    float z = 0.f;
    for (int cb = 0; cb < 248; cb += 8) {
        float tmp[8];
        #pragma unroll
        for (int i = 0; i < 8; ++i) tmp[i] = ebuf[(size_t)(cb + i) * HH_ + e];
        #pragma unroll
        for (int i = 0; i < 8; ++i) {
            z = fmaf(l16, z, tmp[i]);
            ebuf[(size_t)(cb + i) * HH_ + e] = z;
        }
    }
    {   // tail: chunks 248..254
        float tmp[7];
        #pragma unroll
        for (int i = 0; i < 7; ++i) tmp[i] = ebuf[(size_t)(248 + i) * HH_ + e];
        #pragma unroll
        for (int i = 0; i < 7; ++i) {
            z = fmaf(l16, z, tmp[i]);
            ebuf[(size_t)(248 + i) * HH_ + e] = z;
        }
    }
}

// ---- un-hoistable LDS reads: 4 x ds_read_b128 (one nt-group of C-fragments) ----
#define DSR4(d0, d1, d2, d3, addr)                                        \
    asm volatile("ds_read_b128 %0, %4 offset:0\n\t"                       \
                 "ds_read_b128 %1, %4 offset:1024\n\t"                    \
                 "ds_read_b128 %2, %4 offset:2048\n\t"                    \
                 "ds_read_b128 %3, %4 offset:3072"                        \
                 : "=&v"(d0), "=&v"(d1), "=&v"(d2), "=&v"(d3) : "v"(addr))

#define MF(A, B, ACC) __builtin_amdgcn_mfma_f32_16x16x32_bf16(                  \
    __builtin_bit_cast(bf16x8, A), __builtin_bit_cast(bf16x8, B), ACC, 0, 0, 0)

// one output nt-tile: issue next group's reads, wait current (counted), 4 MFMA, store
#define STEP(NT, C0, C1, C2, C3, N0, N1, N2, N3) do {                           \
    if ((NT) < 7) { DSR4(N0, N1, N2, N3, cb0 + ((NT) + 1) * 4096);              \
                    asm volatile("s_waitcnt lgkmcnt(4)"); }                     \
    else          { asm volatile("s_waitcnt lgkmcnt(0)"); }                     \
    __builtin_amdgcn_sched_barrier(0);                                          \
    f32x4 acc = {0.f, 0.f, 0.f, 0.f};                                           \
    acc = MF(za[0], C0, acc); acc = MF(za[1], C1, acc);                         \
    acc = MF(za[2], C2, acc); acc = MF(za[3], C3, acc);                         \
    *(f32x4*)(ops + (NT) * 2048) = acc;                                         \
} while (0)

// ---------------- pass 3: fused scan-replay + MFMA ----------------
// block = 256 thr = 4 waves, all same (chunk c, half): wave w owns a-tile
// a0 = blockIdx.y*64 + w*16. half=0 outputs t0..t0+8; half=1 silently replays
// 8 steps then outputs t0+8..t1. Scan registers ARE the MFMA A-fragments
// (a = a0+(lane&15), k = cc*32+(lane>>4)*8). C-fragments staged once in LDS,
// streamed per-t via volatile asm ds_read (cannot be hoisted -> no spill),
// pipelined one group ahead with counted lgkmcnt. One barrier total.
__global__ __launch_bounds__(256, 2) void pass3_kernel(const float* __restrict__ X,
                                                       const float* __restrict__ Lam,
                                                       const float* __restrict__ Cm,
                                                       const float* __restrict__ wq,
                                                       const float* __restrict__ Dv,
                                                       const float* __restrict__ carry,
                                                       float* __restrict__ out,
                                                       float* __restrict__ os) {
    __shared__ unsigned short cbf[32 * 64 * 8];   // 32 KB: frag f at f*1024 + lane*16

    const int tid  = threadIdx.x;
    const int lane = tid & 63, wave = tid >> 6;
    const int c    = blockIdx.x;
    const int half = blockIdx.z;
    const int a0   = blockIdx.y * 64 + wave * 16;
    const int m    = lane & 15, q = lane >> 4;
    const int a    = a0 + m;

    // ---- stage C-fragments into LDS (frag f = nt*4+cc) ----
    #pragma unroll
    for (int it = 0; it < 8; ++it) {
        const int gid = it * 256 + tid;          // 0..2047 = f*64 + lg
        const int f = gid >> 6, lg = gid & 63;
        const int n  = (f >> 2) * 16 + (lg & 15);
        const int k0 = (f & 3) * 32 + (lg >> 4) * 8;
        const float* src = Cm + (size_t)n * H_ + k0;
        ushort8 v;
        #pragma unroll
        for (int j = 0; j < 8; ++j) v[j] = f2bf(src[j]);
        *(ushort8*)&cbf[(size_t)gid * 8] = v;
    }
    __syncthreads();

    unsigned cb0;
    {   // 32-bit LDS byte address for asm ds_read
        __attribute__((address_space(3))) unsigned short* p3 =
            (__attribute__((address_space(3))) unsigned short*)cbf;
        cb0 = (unsigned)(unsigned long long)p3 + (unsigned)(lane * 16);
    }

    // ---- scan state: z/lam in A-fragment ownership ----
    float z[4][8], lam[4][8];
    #pragma unroll
    for (int cc = 0; cc < 4; ++cc) {
        const int k0 = cc * 32 + q * 8;
        const float* lp = Lam + (size_t)a * H_ + k0;
        #pragma unroll
        for (int j = 0; j < 8; ++j) lam[cc][j] = lp[j];
        if (c == 0) {
            #pragma unroll
            for (int j = 0; j < 8; ++j) z[cc][j] = 0.f;
        } else {
            const float* cp = carry + (size_t)(c - 1) * HH_ + (size_t)a * H_ + k0;
            #pragma unroll
            for (int j = 0; j < 8; ++j) z[cc][j] = cp[j];
        }
    }
    const float wq0 = wq[0], wq1 = wq[1], wq2 = wq[2];
    const float wq3 = wq[3], wq4 = wq[4], wq5 = wq[5];
    const float wq6 = wq[6], wq7 = wq[7], wq8 = wq[8];
    const float dv0 = Dv[0], dv1 = Dv[1], dv2 = Dv[2];

    const int t0 = c * CH_;

    // ---- silent replay (half==1): scan only, no MFMA/stores ----
    if (half) {
        for (int t = t0; t < t0 + 8; ++t) {
            const float* xr = X + (size_t)(2 * t) * H_;
            const float xa0 = xr[a], xa1 = xr[H_ + a], xa2 = xr[2 * H_ + a];
            const float g0 = wq0 * xa0 + wq3 * xa1 + wq6 * xa2;
            const float g1 = wq1 * xa0 + wq4 * xa1 + wq7 * xa2;
            const float g2 = wq2 * xa0 + wq5 * xa1 + wq8 * xa2;
            #pragma unroll
            for (int cc = 0; cc < 4; ++cc) {
                const int k0 = cc * 32 + q * 8;
                f32x4 x0a = *(const f32x4*)(xr + k0),          x0b = *(const f32x4*)(xr + k0 + 4);
                f32x4 x1a = *(const f32x4*)(xr + H_ + k0),     x1b = *(const f32x4*)(xr + H_ + k0 + 4);
                f32x4 x2a = *(const f32x4*)(xr + 2 * H_ + k0), x2b = *(const f32x4*)(xr + 2 * H_ + k0 + 4);
                #pragma unroll
                for (int j = 0; j < 4; ++j) {
                    z[cc][j]     = fmaf(lam[cc][j],     z[cc][j],
                                        g0 * x0a[j] + g1 * x1a[j] + g2 * x2a[j]);
                    z[cc][j + 4] = fmaf(lam[cc][j + 4], z[cc][j + 4],
                                        g0 * x0b[j] + g1 * x1b[j] + g2 * x2b[j]);
                }
            }
        }
    }

    const int tb = t0 + 8 * half;
    const int tmax = t0 + 8 * (half + 1);
    const int te = (tmax < T_) ? tmax : T_;
    const bool do_os = (blockIdx.y == 0) && (wave == 0);

    // ---- output loop: scan + za + pipelined ds_read/MFMA/store, no barriers ----
    for (int t = tb; t < te; ++t) {
        const float* xr = X + (size_t)(2 * t) * H_;
        const float xa0 = xr[a], xa1 = xr[H_ + a], xa2 = xr[2 * H_ + a];
        const float g0 = wq0 * xa0 + wq3 * xa1 + wq6 * xa2;
        const float g1 = wq1 * xa0 + wq4 * xa1 + wq7 * xa2;
        const float g2 = wq2 * xa0 + wq5 * xa1 + wq8 * xa2;
        ushort8 za[4];
        #pragma unroll
        for (int cc = 0; cc < 4; ++cc) {
            const int k0 = cc * 32 + q * 8;
            f32x4 x0a = *(const f32x4*)(xr + k0),          x0b = *(const f32x4*)(xr + k0 + 4);
            f32x4 x1a = *(const f32x4*)(xr + H_ + k0),     x1b = *(const f32x4*)(xr + H_ + k0 + 4);
            f32x4 x2a = *(const f32x4*)(xr + 2 * H_ + k0), x2b = *(const f32x4*)(xr + 2 * H_ + k0 + 4);
            ushort8 zb;
            #pragma unroll
            for (int j = 0; j < 4; ++j) {
                z[cc][j]     = fmaf(lam[cc][j],     z[cc][j],
                                    g0 * x0a[j] + g1 * x1a[j] + g2 * x2a[j]);
                zb[j] = f2bf(z[cc][j]);
                z[cc][j + 4] = fmaf(lam[cc][j + 4], z[cc][j + 4],
                                    g0 * x0b[j] + g1 * x1b[j] + g2 * x2b[j]);
                zb[j + 4] = f2bf(z[cc][j + 4]);
            }
            za[cc] = zb;
        }
        if (do_os) {
            const float s0 = xr[lane], s1 = xr[H_ + lane], s2 = xr[2 * H_ + lane];
            os[(size_t)t * H_ + lane] = dv0 * s0 + dv1 * s1 + dv2 * s2;
            const float u0 = xr[64 + lane], u1 = xr[H_ + 64 + lane], u2 = xr[2 * H_ + 64 + lane];
            os[(size_t)t * H_ + 64 + lane] = dv0 * u0 + dv1 * u1 + dv2 * u2;
        }
        float* ops = out + (size_t)t * HH_ + (size_t)m * H_ + (a0 + q * 4);
        v4i A0, A1, A2, A3, B0, B1, B2, B3;
        DSR4(A0, A1, A2, A3, cb0);
        STEP(0, A0, A1, A2, A3, B0, B1, B2, B3);
        STEP(1, B0, B1, B2, B3, A0, A1, A2, A3);
        STEP(2, A0, A1, A2, A3, B0, B1, B2, B3);
        STEP(3, B0, B1, B2, B3, A0, A1, A2, A3);
        STEP(4, A0, A1, A2, A3, B0, B1, B2, B3);
        STEP(5, B0, B1, B2, B3, A0, A1, A2, A3);
        STEP(6, A0, A1, A2, A3, B0, B1, B2, B3);
        STEP(7, B0, B1, B2, B3, A0, A1, A2, A3);
    }
}

extern "C" void kernel_launch(void* const* d_in, const int* in_sizes, int n_in,
                              void* d_out, int out_size, void* d_ws, size_t ws_size,
                              hipStream_t stream) {
    const float* X   = (const float*)d_in[0];   // (L, H)
    const float* Lam = (const float*)d_in[1];   // (H, H)
    const float* Cm  = (const float*)d_in[2];   // (H, H)
    const float* wq  = (const float*)d_in[3];   // (3, 3)
    const float* Dv  = (const float*)d_in[4];   // (3,)
    float* out  = (float*)d_out;                // zs_out (T,H,H) then os (T,H)
    float* os   = out + (size_t)T_ * HH_;
    float* ebuf = (float*)d_ws;                 // 255 end/carry slots = 15.9 MiB

    pass1_kernel<<<dim3(NC_ - 1, 8), 256, 0, stream>>>(X, Lam, wq, ebuf);
    pass2_kernel<<<64, 256, 0, stream>>>(Lam, ebuf);
    pass3_kernel<<<dim3(NC_, 2, 2), 256, 0, stream>>>(X, Lam, Cm, wq, Dv, ebuf, out, os);
}

// Round 5
// 357.926 us; speedup vs baseline: 1.3567x; 1.1717x over previous
//
#include <hip/hip_runtime.h>

#define L_   8192
#define H_   128
#define T_   4095      // (8192-3)/2 + 1
#define CH_  16        // scan chunk length
#define NC_  256       // number of chunks (255 full + 1 of 15)
#define HH_  (H_ * H_) // 16384

typedef __bf16 bf16x8 __attribute__((ext_vector_type(8)));
typedef unsigned short ushort8 __attribute__((ext_vector_type(8)));
typedef float f32x4 __attribute__((ext_vector_type(4)));

__device__ __forceinline__ unsigned short f2bf(float f) {
    // round-to-nearest-even fp32 -> bf16 bits (matches all previously passing rounds)
    unsigned int u = __builtin_bit_cast(unsigned int, f);
    u += 0x7fffu + ((u >> 16) & 1u);
    return (unsigned short)(u >> 16);
}

// ---------------- pass 1: barrier-free per-chunk local scan ends (g-trick) --------
// u[a][d] = sum_v g_v * x_v[d],  g_v = sum_w wq[w][v] * x[w][a]  (4 ops/elem).
// Verified passing in round 3.
__global__ __launch_bounds__(256) void pass1_kernel(const float* __restrict__ X,
                                                    const float* __restrict__ Lam,
                                                    const float* __restrict__ wq,
                                                    float* __restrict__ ebuf) {
    const int tid = threadIdx.x;
    const int c   = blockIdx.x;            // 0..254 (chunk 255's end is unused)
    const int a   = blockIdx.y * 16 + (tid & 15);
    const int d0  = (tid >> 4) * 8;

    float z[8], lam[8];
    {
        const float* lp = Lam + (size_t)a * H_ + d0;
        #pragma unroll
        for (int j = 0; j < 8; ++j) { lam[j] = lp[j]; z[j] = 0.f; }
    }
    const float wq0 = wq[0], wq1 = wq[1], wq2 = wq[2];
    const float wq3 = wq[3], wq4 = wq[4], wq5 = wq[5];
    const float wq6 = wq[6], wq7 = wq[7], wq8 = wq[8];

    const int t0 = c * CH_;
    for (int t = t0; t < t0 + CH_; ++t) {
        const float* xr = X + (size_t)(2 * t) * H_;
        const float xa0 = xr[a], xa1 = xr[H_ + a], xa2 = xr[2 * H_ + a];
        const float g0 = wq0 * xa0 + wq3 * xa1 + wq6 * xa2;
        const float g1 = wq1 * xa0 + wq4 * xa1 + wq7 * xa2;
        const float g2 = wq2 * xa0 + wq5 * xa1 + wq8 * xa2;
        f32x4 x0a = *(const f32x4*)(xr + d0),           x0b = *(const f32x4*)(xr + d0 + 4);
        f32x4 x1a = *(const f32x4*)(xr + H_ + d0),      x1b = *(const f32x4*)(xr + H_ + d0 + 4);
        f32x4 x2a = *(const f32x4*)(xr + 2 * H_ + d0),  x2b = *(const f32x4*)(xr + 2 * H_ + d0 + 4);
        #pragma unroll
        for (int j = 0; j < 4; ++j) {
            z[j]     = fmaf(lam[j],     z[j],     g0 * x0a[j] + g1 * x1a[j] + g2 * x2a[j]);
            z[j + 4] = fmaf(lam[j + 4], z[j + 4], g0 * x0b[j] + g1 * x1b[j] + g2 * x2b[j]);
        }
    }
    float* ep = ebuf + (size_t)c * HH_ + (size_t)a * H_ + d0;
    f32x4 zlo = {z[0], z[1], z[2], z[3]};
    f32x4 zhi = {z[4], z[5], z[6], z[7]};
    *(f32x4*)ep       = zlo;
    *(f32x4*)(ep + 4) = zhi;
}

// ---------------- pass 2: cross-chunk scan, in place ebuf -> carry ----------------
// After this, slot c (c=0..254) holds carry for chunk c+1; chunk 0 carry = 0.
__global__ __launch_bounds__(256) void pass2_kernel(const float* __restrict__ Lam,
                                                    float* __restrict__ ebuf) {
    const int e = blockIdx.x * 256 + threadIdx.x;
    const float lam = Lam[e];
    float p2 = lam * lam, p4 = p2 * p2, p8 = p4 * p4;
    const float l16 = p8 * p8;
    float z = 0.f;
    for (int cb = 0; cb < 248; cb += 8) {
        float tmp[8];
        #pragma unroll
        for (int i = 0; i < 8; ++i) tmp[i] = ebuf[(size_t)(cb + i) * HH_ + e];
        #pragma unroll
        for (int i = 0; i < 8; ++i) {
            z = fmaf(l16, z, tmp[i]);
            ebuf[(size_t)(cb + i) * HH_ + e] = z;
        }
    }
    {   // tail: chunks 248..254
        float tmp[7];
        #pragma unroll
        for (int i = 0; i < 7; ++i) tmp[i] = ebuf[(size_t)(248 + i) * HH_ + e];
        #pragma unroll
        for (int i = 0; i < 7; ++i) {
            z = fmaf(l16, z, tmp[i]);
            ebuf[(size_t)(248 + i) * HH_ + e] = z;
        }
    }
}

// ---------------- pass 3: LDS-mediated scan + MFMA, 2 t's per barrier group -------
// block: (chunk c, a-tile of 32), 256 thr = 4 waves. Per pair {t, t+1}:
//   [stage 5 raw X rows -> LDS]  barrier
//   [scan both t's in regs (g-trick), publish 2 XOR-swizzled bf16 z-tiles]  barrier
//   [os + MFMA both tiles vs register-resident cfrag, dwordx4 stores]  barrier(top)
// 1.5 barriers/t (r0 had 3/t). z_s layout = r1-passC's measured-0-conflict swizzle.
__global__ __launch_bounds__(256, 2) void pass3_kernel(const float* __restrict__ X,
                                                       const float* __restrict__ Lam,
                                                       const float* __restrict__ Cm,
                                                       const float* __restrict__ wq,
                                                       const float* __restrict__ Dv,
                                                       const float* __restrict__ carry,
                                                       float* __restrict__ out,
                                                       float* __restrict__ os) {
    __shared__ float x5[5][128];                    // 2.5 KB raw X rows (windows overlap)
    __shared__ unsigned short z_s[2][32 * 128];     // 2 x 8 KB, 256B pitch, XOR-swizzled

    const int tid  = threadIdx.x;
    const int c    = blockIdx.x;
    const int a0   = blockIdx.y * 32;
    const int lane = tid & 63, wave = tid >> 6;
    const int m    = lane & 15, q = lane >> 4;

    // B-fragments (N=h): lane holds C[(wave*2+ni)*16+m][kt*32+q*8+j]; resident.
    ushort8 cfrag[2][4];
    #pragma unroll
    for (int ni = 0; ni < 2; ++ni) {
        const int h = (wave * 2 + ni) * 16 + m;
        #pragma unroll
        for (int kt = 0; kt < 4; ++kt) {
            const float* src = Cm + (size_t)h * H_ + kt * 32 + q * 8;
            ushort8 v;
            #pragma unroll
            for (int j = 0; j < 8; ++j) v[j] = f2bf(src[j]);
            cfrag[ni][kt] = v;
        }
    }

    // scan ownership: a_l = tid&31 (one a-row), d = dg*16 + j (16 entries)
    const int a_l = tid & 31;
    const int dg  = tid >> 5;
    const int a   = a0 + a_l;
    float z[16], lam[16];
    {
        const float* lp = Lam + (size_t)a * H_ + dg * 16;
        #pragma unroll
        for (int j = 0; j < 16; ++j) lam[j] = lp[j];
        if (c == 0) {
            #pragma unroll
            for (int j = 0; j < 16; ++j) z[j] = 0.f;
        } else {
            const float* cp = carry + (size_t)(c - 1) * HH_ + (size_t)a * H_ + dg * 16;
            #pragma unroll
            for (int j = 0; j < 16; ++j) z[j] = cp[j];
        }
    }
    const float wq0 = wq[0], wq1 = wq[1], wq2 = wq[2];
    const float wq3 = wq[3], wq4 = wq[4], wq5 = wq[5];
    const float wq6 = wq[6], wq7 = wq[7], wq8 = wq[8];
    const float dv0 = Dv[0], dv1 = Dv[1], dv2 = Dv[2];
    const bool do_os = (blockIdx.y == 0);

    const int t0 = c * CH_, t1 = min(t0 + CH_, T_);

    // scan one t-slot (x rows 2s..2s+2) and publish bf16 tile to z_s[s]
    auto scan_pub = [&](int S) {
        const float xa0 = x5[2 * S][a], xa1 = x5[2 * S + 1][a], xa2 = x5[2 * S + 2][a];
        const float g0 = wq0 * xa0 + wq3 * xa1 + wq6 * xa2;
        const float g1 = wq1 * xa0 + wq4 * xa1 + wq7 * xa2;
        const float g2 = wq2 * xa0 + wq5 * xa1 + wq8 * xa2;
        ushort8 zb0, zb1;
        #pragma unroll
        for (int jj = 0; jj < 2; ++jj) {
            f32x4 xv0a = *(const f32x4*)&x5[2 * S][dg * 16 + jj * 8];
            f32x4 xv0b = *(const f32x4*)&x5[2 * S][dg * 16 + jj * 8 + 4];
            f32x4 xv1a = *(const f32x4*)&x5[2 * S + 1][dg * 16 + jj * 8];
            f32x4 xv1b = *(const f32x4*)&x5[2 * S + 1][dg * 16 + jj * 8 + 4];
            f32x4 xv2a = *(const f32x4*)&x5[2 * S + 2][dg * 16 + jj * 8];
            f32x4 xv2b = *(const f32x4*)&x5[2 * S + 2][dg * 16 + jj * 8 + 4];
            #pragma unroll
            for (int j = 0; j < 4; ++j) {
                const int j8 = jj * 8 + j;
                z[j8]     = fmaf(lam[j8], z[j8],
                                 g0 * xv0a[j] + g1 * xv1a[j] + g2 * xv2a[j]);
                z[j8 + 4] = fmaf(lam[j8 + 4], z[j8 + 4],
                                 g0 * xv0b[j] + g1 * xv1b[j] + g2 * xv2b[j]);
                if (jj == 0) { zb0[j] = f2bf(z[j8]); zb0[j + 4] = f2bf(z[j8 + 4]); }
                else         { zb1[j] = f2bf(z[j8]); zb1[j + 4] = f2bf(z[j8 + 4]); }
            }
        }
        char* zrow = (char*)&z_s[S][0] + a_l * 256;
        const int sw = (a_l & 15) << 4;
        *(ushort8*)(zrow + ((dg * 32) ^ sw))      = zb0;
        *(ushort8*)(zrow + ((dg * 32 + 16) ^ sw)) = zb1;
    };

    // MFMA + store for t-slot S (output row TT)
    auto mfma_store = [&](int S, int TT) {
        f32x4 acc[2][2] = {};
        const char* zbase = (const char*)&z_s[S][0];
        #pragma unroll
        for (int kt = 0; kt < 4; ++kt) {
            const int cb = (kt * 64 + q * 16) ^ (m << 4);
            bf16x8 za = *(const bf16x8*)(zbase + m * 256 + cb);
            bf16x8 zB = *(const bf16x8*)(zbase + (16 + m) * 256 + cb);
            #pragma unroll
            for (int ni = 0; ni < 2; ++ni) {
                bf16x8 cf = __builtin_bit_cast(bf16x8, cfrag[ni][kt]);
                acc[0][ni] = __builtin_amdgcn_mfma_f32_16x16x32_bf16(za, cf, acc[0][ni], 0, 0, 0);
                acc[1][ni] = __builtin_amdgcn_mfma_f32_16x16x32_bf16(zB, cf, acc[1][ni], 0, 0, 0);
            }
        }
        float* ob = out + (size_t)TT * HH_ + a0;
        #pragma unroll
        for (int mi = 0; mi < 2; ++mi) {
            #pragma unroll
            for (int ni = 0; ni < 2; ++ni) {
                const int h = (wave * 2 + ni) * 16 + m;
                *(f32x4*)&ob[(size_t)h * H_ + mi * 16 + q * 4] = acc[mi][ni];
            }
        }
    };

    for (int t = t0; t < t1; t += 2) {
        const bool two = (t + 1 < t1);
        __syncthreads();   // z_s consumed (prev MFMA), x5 consumed (prev scan/os)
        {   // stage 5 (or 3) raw X rows, coalesced
            const float* xb = X + (size_t)(2 * t) * H_;
            const int nid = two ? 640 : 384;
            #pragma unroll
            for (int k = 0; k < 3; ++k) {
                const int id = k * 256 + tid;
                if (id < nid) x5[id >> 7][id & 127] = xb[(size_t)(id >> 7) * H_ + (id & 127)];
            }
        }
        __syncthreads();
        scan_pub(0);
        if (two) scan_pub(1);
        __syncthreads();
        if (do_os && tid < 128) {
            os[(size_t)t * H_ + tid] = dv0 * x5[0][tid] + dv1 * x5[1][tid] + dv2 * x5[2][tid];
            if (two)
                os[(size_t)(t + 1) * H_ + tid] = dv0 * x5[2][tid] + dv1 * x5[3][tid] + dv2 * x5[4][tid];
        }
        mfma_store(0, t);
        if (two) mfma_store(1, t + 1);
    }
}

extern "C" void kernel_launch(void* const* d_in, const int* in_sizes, int n_in,
                              void* d_out, int out_size, void* d_ws, size_t ws_size,
                              hipStream_t stream) {
    const float* X   = (const float*)d_in[0];   // (L, H)
    const float* Lam = (const float*)d_in[1];   // (H, H)
    const float* Cm  = (const float*)d_in[2];   // (H, H)
    const float* wq  = (const float*)d_in[3];   // (3, 3)
    const float* Dv  = (const float*)d_in[4];   // (3,)
    float* out  = (float*)d_out;                // zs_out (T,H,H) then os (T,H)
    float* os   = out + (size_t)T_ * HH_;
    float* ebuf = (float*)d_ws;                 // 255 end/carry slots = 15.9 MiB

    pass1_kernel<<<dim3(NC_ - 1, 8), 256, 0, stream>>>(X, Lam, wq, ebuf);
    pass2_kernel<<<64, 256, 0, stream>>>(Lam, ebuf);
    pass3_kernel<<<dim3(NC_, 4), 256, 0, stream>>>(X, Lam, Cm, wq, Dv, ebuf, out, os);
}